// Round 1
// baseline (212.885 us; speedup 1.0000x reference)
//
#include <hip/hip_runtime.h>

// XMaskSwitchTop2Hard: per-4-group top-2 hard gate mixed with sigmoid(gate_logits).
// Forward math: gate_raw = gate_hard - sg(gate_soft) + gate_soft == gate_hard
// up to ~1 ulp of gate_soft (<=2.4e-7), far below the 0.108 absmax threshold,
// so softmax is skipped. out[j] = keep_j ? x_j : r[g]*x_j, with top_k's
// lowest-index-wins tie-break replicated via stable ranking.

#define GROUPS_PER_ROW 1024  // 4096 hidden / GROUP=4

__global__ __launch_bounds__(256)
void xmask_top2_kernel(const float4* __restrict__ x4,
                       const float* __restrict__ gate_logits,
                       float4* __restrict__ out4,
                       long long ngroups) {
    __shared__ float r_lds[GROUPS_PER_ROW];
    // Build sigmoid table once per block (1024 entries, 4 per thread @ 256 thr).
    for (int i = threadIdx.x; i < GROUPS_PER_ROW; i += blockDim.x) {
        float gl = gate_logits[i];
        r_lds[i] = 1.0f / (1.0f + expf(-gl));
    }
    __syncthreads();

    const long long stride = (long long)gridDim.x * blockDim.x;
    for (long long gi = (long long)blockIdx.x * blockDim.x + threadIdx.x;
         gi < ngroups; gi += stride) {
        float4 v = x4[gi];
        float r = r_lds[(int)(gi & (GROUPS_PER_ROW - 1))];

        float s0 = fabsf(v.x), s1 = fabsf(v.y), s2 = fabsf(v.z), s3 = fabsf(v.w);

        // rank_j = count of i beating j; i beats j iff s_i > s_j, or tie with i<j.
        int c0 = (s1 >  s0) + (s2 >  s0) + (s3 >  s0);
        int c1 = (s0 >= s1) + (s2 >  s1) + (s3 >  s1);
        int c2 = (s0 >= s2) + (s1 >= s2) + (s3 >  s2);
        int c3 = (s0 >= s3) + (s1 >= s3) + (s2 >= s3);

        float4 o;
        o.x = (c0 < 2) ? v.x : r * v.x;
        o.y = (c1 < 2) ? v.y : r * v.y;
        o.z = (c2 < 2) ? v.z : r * v.z;
        o.w = (c3 < 2) ? v.w : r * v.w;
        out4[gi] = o;
    }
}

extern "C" void kernel_launch(void* const* d_in, const int* in_sizes, int n_in,
                              void* d_out, int out_size, void* d_ws, size_t ws_size,
                              hipStream_t stream) {
    const float4* x4 = (const float4*)d_in[0];
    const float* gate_logits = (const float*)d_in[1];
    float4* out4 = (float4*)d_out;

    long long ngroups = (long long)out_size / 4;  // 134217728 / 4 = 33554432

    const int threads = 256;
    const int blocks = 2048;  // 256 CU x 8, grid-stride covers the rest
    xmask_top2_kernel<<<blocks, threads, 0, stream>>>(x4, gate_logits, out4, ngroups);
}